// Round 7
// baseline (996.310 us; speedup 1.0000x reference)
//
#include <hip/hip_runtime.h>
#include <cstdint>
#include <cstddef>

#define DEV __device__ __forceinline__
#define AS1 __attribute__((address_space(1)))
#define AS3 __attribute__((address_space(3)))

typedef unsigned short u16;
typedef unsigned char u8;
typedef long long ll;

typedef __attribute__((ext_vector_type(8))) __bf16 bf16x8;
typedef __attribute__((ext_vector_type(8))) unsigned short u16x8;
typedef __attribute__((ext_vector_type(4))) float f32x4;

static constexpr int SEQ  = 720;
static constexpr int ENC  = 862;
static constexpr int NTOK = 866;            // ENC + MARK
static constexpr int DM   = 256;
static constexpr int G16  = 16;             // B * T_SCALES
static constexpr int MTOT = G16 * NTOK;     // 13856
static constexpr int KPAD = 736;            // SEQ padded to multiple of 32
static constexpr int SPAD = 896;            // 866 keys padded to multiple of 32
static constexpr float SC2 = 0.17677669529663689f * 1.4426950408889634f; // scale*log2e

DEV float b2f(u16 v){ union { unsigned u; float f; } x; x.u = ((unsigned)v) << 16; return x.f; }
DEV u16 f2b(float f){ union { float f; unsigned u; } x; x.f = f;
  unsigned r = x.u + 0x7fffu + ((x.u >> 16) & 1u); return (u16)(r >> 16); }
DEV bf16x8 as_bf(u16x8 v){ return __builtin_bit_cast(bf16x8, v); }

// async global->LDS, 16B per lane; LDS base wave-uniform, global per-lane
DEV void g2l(const u16* g, u16* l){
  __builtin_amdgcn_global_load_lds((AS1 void*)g, (AS3 void*)l, 16, 0, 0);
}

// XCD-aware remap for GEMM grids
DEV int xcd_work(){
  int L = blockIdx.y * gridDim.x + blockIdx.x;
  int T = gridDim.x * gridDim.y;
  int x = L & 7, k = L >> 3;
  int q = T >> 3, r = T & 7;
  int mn = x < r ? x : r;
  return x*q + mn + k;
}

// ------------------------------------------------------------------
struct CvtJobs {
  const float* src[10];
  u16* dst[10];
  int n[10];
  int per[10];
  ll stride[10];
};
__global__ __launch_bounds__(256) void cvt_multi(CvtJobs J)
{
  int j = blockIdx.y;
  const float* s = J.src[j];
  u16* d = J.dst[j];
  int n = J.n[j], per = J.per[j];
  ll st = J.stride[j];
  for (int i = blockIdx.x*256 + threadIdx.x; i < n; i += gridDim.x*256) {
    ll di = per ? ((ll)(i/per)*st + (i%per)) : (ll)i;
    d[di] = f2b(s[i]);
  }
}

__global__ __launch_bounds__(256) void pack_bqkv(const float* __restrict__ bq,
                                                 const float* __restrict__ bk,
                                                 const float* __restrict__ bv,
                                                 float* __restrict__ out)
{
  int idx = blockIdx.x*256 + threadIdx.x;
  if (idx >= 1536) return;
  int l = idx / 768, j = idx % 768;
  float v;
  if (j < 256)      v = bq[l*256 + j];
  else if (j < 512) v = bk[l*256 + j - 256];
  else              v = bv[l*256 + j - 512];
  out[idx] = v;
}

// ------------------------------------------------------------------
__global__ __launch_bounds__(256) void stats_kernel(const float* __restrict__ x,
                                                    float* __restrict__ meanp,
                                                    float* __restrict__ stdp)
{
  int g = blockIdx.x >> 2;
  int c = ((blockIdx.x & 3) << 8) + threadIdx.x;
  if (c >= ENC) return;
  const float* xp = x + (ll)g * SEQ * ENC + c;
  float s = 0.f, q = 0.f;
  for (int t = 0; t < SEQ; ++t) {
    float v = xp[(ll)t * ENC];
    s += v; q += v * v;
  }
  float mn  = s * (1.f / SEQ);
  float var = q * (1.f / SEQ) - mn * mn;
  var = var < 0.f ? 0.f : var;
  meanp[g * ENC + c] = mn;
  stdp [g * ENC + c] = sqrtf(var + 1e-5f);
}

// ------------------------------------------------------------------
__global__ __launch_bounds__(256) void build_xin(const float* __restrict__ x,
                                                 const float* __restrict__ xm,
                                                 const float* __restrict__ meanp,
                                                 const float* __restrict__ stdp,
                                                 u16* __restrict__ xin)
{
  int g  = blockIdx.z;
  int c0 = blockIdx.x << 5, s0 = blockIdx.y << 5;
  __shared__ float tl[32][33];
  __shared__ float mn[32], isd[32];
  int tid = threadIdx.x;
  if (tid < 32) {
    int c = c0 + tid;
    float m = 0.f, s = 1.f;
    if (c < ENC) { m = meanp[g*ENC + c]; s = stdp[g*ENC + c]; }
    mn[tid] = m; isd[tid] = 1.f / s;
  }
  __syncthreads();
  int ci = tid & 31, r = tid >> 5;
  #pragma unroll
  for (int p = 0; p < 4; ++p) {
    int sl = r + (p << 3);
    int s = s0 + sl, c = c0 + ci;
    float v = 0.f;
    if (s < SEQ && c < NTOK) {
      if (c < ENC) v = (x[((ll)g*SEQ + s)*ENC + c] - mn[ci]) * isd[ci];
      else         v = xm[((ll)g*SEQ + s)*4 + (c - ENC)];
    }
    tl[sl][ci] = v;
  }
  __syncthreads();
  int si = tid & 31;
  #pragma unroll
  for (int p = 0; p < 4; ++p) {
    int cl = r + (p << 3);
    int c = c0 + cl;
    if (c < NTOK) xin[((ll)g*NTOK + c)*KPAD + s0 + si] = f2b(tl[si][cl]);
  }
}

// ------------------------------------------------------------------
__global__ __launch_bounds__(256) void pack_embedw(const float* __restrict__ ew,
                                                   u16* __restrict__ wp)
{
  int row = blockIdx.x;
  for (int c = threadIdx.x; c < KPAD; c += 256)
    wp[row*KPAD + c] = (c < SEQ) ? f2b(ew[row*SEQ + c]) : (u16)0;
}

// ------------------------------------------------------------------
__global__ __launch_bounds__(256) void transpose_v(const u16* __restrict__ v, int ldv,
                                                   u16* __restrict__ vT)
{
  int g = blockIdx.z;
  int d0 = blockIdx.x << 5, s0 = blockIdx.y << 5;
  __shared__ u16 tl[32][33];
  int tid = threadIdx.x;
  int di = tid & 31, r = tid >> 5;
  #pragma unroll
  for (int p = 0; p < 4; ++p) {
    int sl = r + (p << 3);
    int s = s0 + sl;
    u16 val = 0;
    if (s < NTOK) val = v[((ll)g*NTOK + s)*ldv + d0 + di];
    tl[sl][di] = val;
  }
  __syncthreads();
  int si = tid & 31;
  #pragma unroll
  for (int p = 0; p < 4; ++p) {
    int dl = r + (p << 3);
    vT[((ll)g*DM + d0 + dl)*SPAD + s0 + si] = tl[si][dl];
  }
}

// ------------------------------------------------------------------
// flash attention (unchanged from round 6)
// ------------------------------------------------------------------
__global__ __launch_bounds__(256) void flash_attn(const u16* __restrict__ qb,
                                                  const u16* __restrict__ kb,
                                                  int ldqk,
                                                  const u16* __restrict__ vT,
                                                  u16* __restrict__ attb)
{
  const int w = xcd_work();
  const int gh = w / 7;
  const int g = gh >> 3, h = gh & 7;
  const int q0 = (w % 7) * 128;
  const int tid = threadIdx.x, wv = tid >> 6, lane = tid & 63;
  const int q4 = lane >> 4, c16 = lane & 15;
  constexpr int PLD = 136;

  __shared__ __attribute__((aligned(16))) u16 Qs[128*32];
  __shared__ __attribute__((aligned(16))) u16 Ks[128*32];
  __shared__ __attribute__((aligned(16))) u16 Vs[32*PLD];
  __shared__ __attribute__((aligned(16))) u16 Ps[4][32*PLD];

  {
    int r = tid >> 1, sg = (tid & 1) << 4;
    int row = q0 + r; if (row > NTOK-1) row = NTOK-1;
    const u16* src = qb + ((ll)(g*NTOK + row))*ldqk + h*32 + sg;
    *(uint4*)&Qs[r*32 + sg]     = *(const uint4*)src;
    *(uint4*)&Qs[r*32 + sg + 8] = *(const uint4*)(src + 8);
  }
  __syncthreads();

  bf16x8 qf[2];
  qf[0] = as_bf(*(const u16x8*)&Qs[(wv*32 +      c16)*32 + q4*8]);
  qf[1] = as_bf(*(const u16x8*)&Qs[(wv*32 + 16 + c16)*32 + q4*8]);

  float lsum[2][4] = {{0,0,0,0},{0,0,0,0}};
  f32x4 oacc[2][2];
  oacc[0][0] = (f32x4){0,0,0,0}; oacc[0][1] = (f32x4){0,0,0,0};
  oacc[1][0] = (f32x4){0,0,0,0}; oacc[1][1] = (f32x4){0,0,0,0};

  for (int kt = 0; kt < 7; ++kt) {
    const int k0 = kt * 128;
    if (kt) __syncthreads();
    {
      int r = tid >> 1, sg = (tid & 1) << 4;
      int row = k0 + r; if (row > NTOK-1) row = NTOK-1;
      const u16* src = kb + ((ll)(g*NTOK + row))*ldqk + h*32 + sg;
      *(uint4*)&Ks[r*32 + sg]     = *(const uint4*)src;
      *(uint4*)&Ks[r*32 + sg + 8] = *(const uint4*)(src + 8);
    }
    {
      int e = tid >> 3, sg = (tid & 7) << 4;
      const u16* src = vT + ((ll)(g*DM + h*32 + e))*SPAD + k0 + sg;
      *(uint4*)&Vs[e*PLD + sg]     = *(const uint4*)src;
      *(uint4*)&Vs[e*PLD + sg + 8] = *(const uint4*)(src + 8);
    }
    __syncthreads();

    f32x4 s[2][8];
    #pragma unroll
    for (int i = 0; i < 2; ++i)
      #pragma unroll
      for (int j = 0; j < 8; ++j) s[i][j] = (f32x4){0,0,0,0};
    #pragma unroll
    for (int j = 0; j < 8; ++j) {
      bf16x8 kf = as_bf(*(const u16x8*)&Ks[(j*16 + c16)*32 + q4*8]);
      s[0][j] = __builtin_amdgcn_mfma_f32_16x16x32_bf16(qf[0], kf, s[0][j], 0, 0, 0);
      s[1][j] = __builtin_amdgcn_mfma_f32_16x16x32_bf16(qf[1], kf, s[1][j], 0, 0, 0);
    }
    if (kt == 6) {
      #pragma unroll
      for (int j = 0; j < 8; ++j) {
        if (k0 + j*16 + c16 >= NTOK) {
          #pragma unroll
          for (int r = 0; r < 4; ++r) { s[0][j][r] = -1e30f; s[1][j][r] = -1e30f; }
        }
      }
    }

    #pragma unroll
    for (int i = 0; i < 2; ++i)
      #pragma unroll
      for (int j = 0; j < 8; ++j)
        #pragma unroll
        for (int r = 0; r < 4; ++r) {
          float p = exp2f(s[i][j][r]);
          lsum[i][r] += p;
          unsigned u = __builtin_bit_cast(unsigned, p);
          Ps[wv][(i*16 + q4*4 + r)*PLD + j*16 + c16] = (u16)(u >> 16);
        }

    #pragma unroll
    for (int kk = 0; kk < 4; ++kk) {
      bf16x8 af0 = as_bf(*(const u16x8*)&Ps[wv][(     c16)*PLD + kk*32 + q4*8]);
      bf16x8 af1 = as_bf(*(const u16x8*)&Ps[wv][(16 + c16)*PLD + kk*32 + q4*8]);
      bf16x8 b0  = as_bf(*(const u16x8*)&Vs[(     c16)*PLD + kk*32 + q4*8]);
      bf16x8 b1  = as_bf(*(const u16x8*)&Vs[(16 + c16)*PLD + kk*32 + q4*8]);
      oacc[0][0] = __builtin_amdgcn_mfma_f32_16x16x32_bf16(af0, b0, oacc[0][0], 0, 0, 0);
      oacc[0][1] = __builtin_amdgcn_mfma_f32_16x16x32_bf16(af0, b1, oacc[0][1], 0, 0, 0);
      oacc[1][0] = __builtin_amdgcn_mfma_f32_16x16x32_bf16(af1, b0, oacc[1][0], 0, 0, 0);
      oacc[1][1] = __builtin_amdgcn_mfma_f32_16x16x32_bf16(af1, b1, oacc[1][1], 0, 0, 0);
    }
  }

  float linv[2][4];
  #pragma unroll
  for (int i = 0; i < 2; ++i)
    #pragma unroll
    for (int r = 0; r < 4; ++r) {
      float t = lsum[i][r];
      t += __shfl_xor(t, 1, 64);
      t += __shfl_xor(t, 2, 64);
      t += __shfl_xor(t, 4, 64);
      t += __shfl_xor(t, 8, 64);
      linv[i][r] = 1.f / t;
    }
  #pragma unroll
  for (int i = 0; i < 2; ++i)
    #pragma unroll
    for (int jn = 0; jn < 2; ++jn)
      #pragma unroll
      for (int r = 0; r < 4; ++r) {
        int row = q0 + wv*32 + i*16 + q4*4 + r;
        if (row < NTOK)
          attb[((ll)(g*NTOK + row))*DM + h*32 + jn*16 + c16] =
            f2b(oacc[i][jn][r] * linv[i][r]);
      }
}

// ------------------------------------------------------------------
__global__ __launch_bounds__(256) void final_combine(const u16* __restrict__ outF,
                                                     const float* __restrict__ meanp,
                                                     const float* __restrict__ stdp,
                                                     float* __restrict__ dout)
{
  int b = blockIdx.z;
  int c0 = blockIdx.x << 5, s0 = blockIdx.y << 5;
  __shared__ float tl[32][33];
  int tid = threadIdx.x;
  int si = tid & 31, r = tid >> 5;
  #pragma unroll
  for (int p = 0; p < 4; ++p) {
    int cl = r + (p << 3);
    int c = c0 + cl, s = s0 + si;
    float accv = 0.f;
    #pragma unroll
    for (int t = 0; t < 2; ++t) {
      int g = b*2 + t;
      if (c < ENC && s < SEQ) {
        float v = b2f(outF[((ll)(g*NTOK + c))*SEQ + s]);
        accv += 0.5f * (v * stdp[g*ENC + c] + meanp[g*ENC + c]);
      }
    }
    tl[cl][si] = accv;
  }
  __syncthreads();
  int ci = tid & 31;
  #pragma unroll
  for (int p = 0; p < 4; ++p) {
    int sl = r + (p << 3);
    int s = s0 + sl, c = c0 + ci;
    if (s < SEQ && c < ENC)
      dout[((ll)b*SEQ + s)*ENC + c] = tl[ci][sl];
  }
}

// ------------------------------------------------------------------
// NT GEMM (embed, fused-QKV). XCD swizzle + g2l staging.
// modes: 0 store, 5 qkv (scale cols<256 by SC2)
// ------------------------------------------------------------------
__global__ __launch_bounds__(256) void gemm_nt(
    const u16* __restrict__ A, const u16* __restrict__ B,
    const float* __restrict__ bias, u16* __restrict__ C,
    int M, int N, int K, int lda, int ldb, int ldc, int mode)
{
  __shared__ __attribute__((aligned(16))) u16 As[128*32];
  __shared__ __attribute__((aligned(16))) u16 Bs[128*32];

  const int tid  = threadIdx.x;
  const int wv   = tid >> 6;
  const int lane = tid & 63;
  const int q4   = lane >> 4;
  const int c16  = lane & 15;

  const int w = xcd_work();
  const int n0 = (w % gridDim.x) * 128;
  const int m0 = (w / gridDim.x) * 128;
  const int wm = (wv >> 1) * 64;
  const int wn = (wv & 1) * 64;

  const int lrow = lane >> 2;
  const int lcol = (lane & 3) << 3;
  int am0 = m0 + wv*32 + lrow;      if (am0 >= M) am0 = M-1;
  int am1 = m0 + wv*32 + 16 + lrow; if (am1 >= M) am1 = M-1;
  int bn0 = n0 + wv*32 + lrow;      if (bn0 >= N) bn0 = N-1;
  int bn1 = n0 + wv*32 + 16 + lrow; if (bn1 >= N) bn1 = N-1;
  const u16* pa0 = A + (ll)am0*lda + lcol;
  const u16* pa1 = A + (ll)am1*lda + lcol;
  const u16* pb0 = B + (ll)bn0*ldb + lcol;
  const u16* pb1 = B + (ll)bn1*ldb + lcol;
  u16* dA0 = &As[(wv*32)*32];
  u16* dA1 = &As[(wv*32 + 16)*32];
  u16* dB0 = &Bs[(wv*32)*32];
  u16* dB1 = &Bs[(wv*32 + 16)*32];

  f32x4 acc[4][4];
  #pragma unroll
  for (int i = 0; i < 4; ++i)
    #pragma unroll
    for (int j = 0; j < 4; ++j) acc[i][j] = (f32x4){0,0,0,0};

  const int nk = K >> 5;
  auto issue = [&](int kt) {
    int ko = kt*32;
    g2l(pa0 + ko, dA0); g2l(pa1 + ko, dA1);
    g2l(pb0 + ko, dB0); g2l(pb1 + ko, dB1);
  };

  issue(0);
  for (int kt = 0; kt < nk; ++kt) {
    __syncthreads();

    bf16x8 af[4], bfv[4];
    #pragma unroll
    for (int i = 0; i < 4; ++i)
      af[i] = as_bf(*(const u16x8*)&As[(wm + i*16 + c16)*32 + q4*8]);
    #pragma unroll
    for (int j = 0; j < 4; ++j)
      bfv[j] = as_bf(*(const u16x8*)&Bs[(wn + j*16 + c16)*32 + q4*8]);
    #pragma unroll
    for (int i = 0; i < 4; ++i)
      #pragma unroll
      for (int j = 0; j < 4; ++j)
        acc[i][j] = __builtin_amdgcn_mfma_f32_16x16x32_bf16(af[i], bfv[j], acc[i][j], 0, 0, 0);

    if (kt + 1 < nk) { __syncthreads(); issue(kt + 1); }
  }

  #pragma unroll
  for (int i = 0; i < 4; ++i) {
    #pragma unroll
    for (int j = 0; j < 4; ++j) {
      int n = n0 + wn + j*16 + c16;
      if (n >= N) continue;
      float bv = bias ? bias[n] : 0.f;
      int mb = m0 + wm + i*16 + q4*4;
      #pragma unroll
      for (int r = 0; r < 4; ++r) {
        int m = mb + r;
        if (m >= M) continue;
        float x = acc[i][j][r] + bv;
        ll ci = (ll)m*ldc + n;
        C[ci] = f2b(mode == 5 && n < 256 ? x * SC2 : x);
      }
    }
  }
}

// ------------------------------------------------------------------
// fused FFN + output projection: one block = 64 rows.
// Wo -> LN1 -> W1(gelu) -> W2 -> xs -> W3*W4(dual) -> LN2 -> hb
//   cat=[x_att,y] (LDS) -> W5*W6(dual,N=720) -> outX [- sub]
// ------------------------------------------------------------------
__global__ __launch_bounds__(256, 1) void ffn_fused(
    const u16* __restrict__ attb, u16* __restrict__ hb,
    const u16* __restrict__ Wo, const u16* __restrict__ W1,
    const u16* __restrict__ W2, const u16* __restrict__ W3,
    const u16* __restrict__ W4, const u16* __restrict__ W5,
    const u16* __restrict__ W6,
    const float* __restrict__ bo, const float* __restrict__ b1,
    const float* __restrict__ b2, const float* __restrict__ b3,
    const float* __restrict__ b4, const float* __restrict__ b5,
    const float* __restrict__ b6,
    const float* __restrict__ ln1g, const float* __restrict__ ln1b,
    const float* __restrict__ ln2g, const float* __restrict__ ln2b,
    const u16* __restrict__ sub, u16* __restrict__ outX)
{
  constexpr int XLD = 520;   // 1040 B row stride -> 2-way banks (free)
  constexpr int BLD = 264;   // 528 B row stride  -> 2-way banks (free)
  __shared__ __attribute__((aligned(16))) u16 bufX[64*XLD]; // [xatt | y/t1]
  __shared__ __attribute__((aligned(16))) u16 bufB[64*BLD]; // h -> x_ln -> xs -> hh
  __shared__ __attribute__((aligned(16))) u16 bufW [256*32];
  __shared__ __attribute__((aligned(16))) u16 bufW2[256*32];

  const int tid = threadIdx.x, wv = tid >> 6, lane = tid & 63;
  const int q4 = lane >> 4, c16 = lane & 15;
  const int m0 = blockIdx.x * 64;

  // ---- stage activation rows (clamped) ----
  {
    int r = tid >> 2;
    int row = m0 + r; if (row >= MTOT) row = MTOT - 1;
    const u16* pa = attb + (ll)row*256;
    const u16* ph = hb   + (ll)row*256;
    int cb = (tid & 3) * 64;
    #pragma unroll
    for (int p = 0; p < 8; ++p) {
      *(uint4*)&bufX[r*XLD + cb + p*8] = *(const uint4*)(pa + cb + p*8);
      *(uint4*)&bufB[r*BLD + cb + p*8] = *(const uint4*)(ph + cb + p*8);
    }
  }
  __syncthreads();

  // stage a 256x32 weight k-tile into dst (rows nbase..nbase+255 clamped to nmax)
  auto stageW = [&](u16* dst, const u16* W, int ldw, int kofs, int nbase, int nmax){
    #pragma unroll
    for (int s = 0; s < 4; ++s) {
      int rbase = wv*64 + s*16;
      int row = nbase + rbase + (lane >> 2);
      if (row > nmax) row = nmax;
      g2l(W + (ll)row*ldw + kofs + (lane & 3)*8, dst + rbase*32);
    }
  };
  auto ldA = [&](const u16* buf, int ld, int co, int i, int kt){
    return as_bf(*(const u16x8*)&buf[(i*16 + c16)*ld + co + kt*32 + q4*8]);
  };
  auto ldB = [&](const u16* buf, int j){
    return as_bf(*(const u16x8*)&buf[(wv*64 + j*16 + c16)*32 + q4*8]);
  };

  // ================= GEMM1: x_att = attb @ Wo^T =================
  f32x4 acc[4][4];
  #pragma unroll
  for (int i = 0; i < 4; ++i)
    #pragma unroll
    for (int j = 0; j < 4; ++j) acc[i][j] = (f32x4){0,0,0,0};
  for (int kt = 0; kt < 8; ++kt) {
    stageW(bufW, Wo, 256, kt*32, 0, 255);
    __syncthreads();
    bf16x8 af[4], bb[4];
    #pragma unroll
    for (int i = 0; i < 4; ++i) af[i] = ldA(bufX, XLD, 0, i, kt);
    #pragma unroll
    for (int j = 0; j < 4; ++j) bb[j] = ldB(bufW, j);
    #pragma unroll
    for (int i = 0; i < 4; ++i)
      #pragma unroll
      for (int j = 0; j < 4; ++j)
        acc[i][j] = __builtin_amdgcn_mfma_f32_16x16x32_bf16(af[i], bb[j], acc[i][j], 0, 0, 0);
    __syncthreads();
  }
  // epi1: write x_att into bufX[:,0:256]
  #pragma unroll
  for (int i = 0; i < 4; ++i)
    #pragma unroll
    for (int j = 0; j < 4; ++j) {
      int n = wv*64 + j*16 + c16;
      float bv = bo[n];
      #pragma unroll
      for (int r = 0; r < 4; ++r) {
        int m = i*16 + q4*4 + r;
        bufX[m*XLD + n] = f2b(acc[i][j][r] + bv);
      }
    }
  __syncthreads();

  // ================= LN1: x_ln = LN(h - x_att) -> bufB =================
  {
    int r = tid >> 2, cb = (tid & 3) * 64;
    float sm = 0.f, sq = 0.f;
    #pragma unroll
    for (int c = 0; c < 64; c += 8) {
      u16x8 hv = *(const u16x8*)&bufB[r*BLD + cb + c];
      u16x8 av = *(const u16x8*)&bufX[r*XLD + cb + c];
      #pragma unroll
      for (int e = 0; e < 8; ++e) {
        float d = b2f(hv[e]) - b2f(av[e]);
        sm += d; sq += d*d;
      }
    }
    sm += __shfl_xor(sm, 1, 64); sm += __shfl_xor(sm, 2, 64);
    sq += __shfl_xor(sq, 1, 64); sq += __shfl_xor(sq, 2, 64);
    float mu = sm * (1.f/256.f);
    float var = sq * (1.f/256.f) - mu*mu; var = var < 0.f ? 0.f : var;
    float rstd = 1.f / sqrtf(var + 1e-5f);
    #pragma unroll
    for (int c = 0; c < 64; c += 8) {
      u16x8 hv = *(const u16x8*)&bufB[r*BLD + cb + c];
      u16x8 av = *(const u16x8*)&bufX[r*XLD + cb + c];
      u16x8 o;
      #pragma unroll
      for (int e = 0; e < 8; ++e) {
        float d = b2f(hv[e]) - b2f(av[e]);
        o[e] = f2b((d - mu)*rstd*ln1g[cb+c+e] + ln1b[cb+c+e]);
      }
      *(u16x8*)&bufB[r*BLD + cb + c] = o;
    }
  }
  __syncthreads();

  // ================= GEMM2/3: y = gelu(x_ln@W1^T+b1)@W2^T =================
  f32x4 yac[4][4];
  #pragma unroll
  for (int i = 0; i < 4; ++i)
    #pragma unroll
    for (int j = 0; j < 4; ++j) yac[i][j] = (f32x4){0,0,0,0};
  #pragma unroll 1
  for (int hf = 0; hf < 2; ++hf) {
    f32x4 a2[4][4];
    #pragma unroll
    for (int i = 0; i < 4; ++i)
      #pragma unroll
      for (int j = 0; j < 4; ++j) a2[i][j] = (f32x4){0,0,0,0};
    for (int kt = 0; kt < 8; ++kt) {
      stageW(bufW, W1, 256, kt*32, hf*256, 511);
      __syncthreads();
      bf16x8 af[4], bb[4];
      #pragma unroll
      for (int i = 0; i < 4; ++i) af[i] = ldA(bufB, BLD, 0, i, kt);
      #pragma unroll
      for (int j = 0; j < 4; ++j) bb[j] = ldB(bufW, j);
      #pragma unroll
      for (int i = 0; i < 4; ++i)
        #pragma unroll
        for (int j = 0; j < 4; ++j)
          a2[i][j] = __builtin_amdgcn_mfma_f32_16x16x32_bf16(af[i], bb[j], a2[i][j], 0, 0, 0);
      __syncthreads();
    }
    // epi2: t1 = gelu -> bufX[:,256:512]
    #pragma unroll
    for (int i = 0; i < 4; ++i)
      #pragma unroll
      for (int j = 0; j < 4; ++j) {
        int n = wv*64 + j*16 + c16;
        float bv = b1[hf*256 + n];
        #pragma unroll
        for (int r = 0; r < 4; ++r) {
          int m = i*16 + q4*4 + r;
          float xg = a2[i][j][r] + bv;
          bufX[m*XLD + 256 + n] = f2b(0.5f*xg*(1.f + erff(xg*0.70710678118654752f)));
        }
      }
    __syncthreads();
    for (int kt = 0; kt < 8; ++kt) {
      stageW(bufW, W2, 512, hf*256 + kt*32, 0, 255);
      __syncthreads();
      bf16x8 af[4], bb[4];
      #pragma unroll
      for (int i = 0; i < 4; ++i) af[i] = ldA(bufX, XLD, 256, i, kt);
      #pragma unroll
      for (int j = 0; j < 4; ++j) bb[j] = ldB(bufW, j);
      #pragma unroll
      for (int i = 0; i < 4; ++i)
        #pragma unroll
        for (int j = 0; j < 4; ++j)
          yac[i][j] = __builtin_amdgcn_mfma_f32_16x16x32_bf16(af[i], bb[j], yac[i][j], 0, 0, 0);
      __syncthreads();
    }
  }
  // epi3: y -> bufX[:,256:512]; xs = x_ln - y -> bufB
  #pragma unroll
  for (int i = 0; i < 4; ++i)
    #pragma unroll
    for (int j = 0; j < 4; ++j) {
      int n = wv*64 + j*16 + c16;
      float bv = b2[n];
      #pragma unroll
      for (int r = 0; r < 4; ++r) {
        int m = i*16 + q4*4 + r;
        float y = yac[i][j][r] + bv;
        float xl = b2f(bufB[m*BLD + n]);
        bufX[m*XLD + 256 + n] = f2b(y);
        bufB[m*BLD + n] = f2b(xl - y);
      }
    }
  __syncthreads();

  // ================= GEMM4 dual: hh = sig(xs@W3^T+b3)*(xs@W4^T+b4) =======
  f32x4 a3[4][4], a4[4][4];
  #pragma unroll
  for (int i = 0; i < 4; ++i)
    #pragma unroll
    for (int j = 0; j < 4; ++j) { a3[i][j] = (f32x4){0,0,0,0}; a4[i][j] = (f32x4){0,0,0,0}; }
  for (int kt = 0; kt < 8; ++kt) {
    stageW(bufW,  W3, 256, kt*32, 0, 255);
    stageW(bufW2, W4, 256, kt*32, 0, 255);
    __syncthreads();
    bf16x8 af[4], b3f[4], b4f[4];
    #pragma unroll
    for (int i = 0; i < 4; ++i) af[i] = ldA(bufB, BLD, 0, i, kt);
    #pragma unroll
    for (int j = 0; j < 4; ++j) { b3f[j] = ldB(bufW, j); b4f[j] = ldB(bufW2, j); }
    #pragma unroll
    for (int i = 0; i < 4; ++i)
      #pragma unroll
      for (int j = 0; j < 4; ++j) {
        a3[i][j] = __builtin_amdgcn_mfma_f32_16x16x32_bf16(af[i], b3f[j], a3[i][j], 0, 0, 0);
        a4[i][j] = __builtin_amdgcn_mfma_f32_16x16x32_bf16(af[i], b4f[j], a4[i][j], 0, 0, 0);
      }
    __syncthreads();
  }
  // epi4: hh -> bufB
  #pragma unroll
  for (int i = 0; i < 4; ++i)
    #pragma unroll
    for (int j = 0; j < 4; ++j) {
      int n = wv*64 + j*16 + c16;
      float bv3 = b3[n], bv4 = b4[n];
      #pragma unroll
      for (int r = 0; r < 4; ++r) {
        int m = i*16 + q4*4 + r;
        float z3 = a3[i][j][r] + bv3;
        float z4 = a4[i][j][r] + bv4;
        bufB[m*BLD + n] = f2b(z4 / (1.f + expf(-z3)));
      }
    }
  __syncthreads();

  // ================= LN2: h_new = LN(hh) -> hb (global) =================
  {
    int r = tid >> 2, cb = (tid & 3) * 64;
    int row = m0 + r;
    float sm = 0.f, sq = 0.f;
    #pragma unroll
    for (int c = 0; c < 64; c += 8) {
      u16x8 hv = *(const u16x8*)&bufB[r*BLD + cb + c];
      #pragma unroll
      for (int e = 0; e < 8; ++e) { float v = b2f(hv[e]); sm += v; sq += v*v; }
    }
    sm += __shfl_xor(sm, 1, 64); sm += __shfl_xor(sm, 2, 64);
    sq += __shfl_xor(sq, 1, 64); sq += __shfl_xor(sq, 2, 64);
    float mu = sm * (1.f/256.f);
    float var = sq * (1.f/256.f) - mu*mu; var = var < 0.f ? 0.f : var;
    float rstd = 1.f / sqrtf(var + 1e-5f);
    if (row < MTOT) {
      #pragma unroll
      for (int c = 0; c < 64; c += 8) {
        u16x8 hv = *(const u16x8*)&bufB[r*BLD + cb + c];
        u16x8 o;
        #pragma unroll
        for (int e = 0; e < 8; ++e)
          o[e] = f2b((b2f(hv[e]) - mu)*rstd*ln2g[cb+c+e] + ln2b[cb+c+e]);
        *(uint4*)(hb + (ll)row*256 + cb + c) = __builtin_bit_cast(uint4, o);
      }
    }
  }

  // ================= G56 dual over cat=[x_att,y]: out -> outX ============
  #pragma unroll 1
  for (int nc = 0; nc < 3; ++nc) {
    int nb = nc * 256;
    f32x4 a5[4][4], a6[4][4];
    #pragma unroll
    for (int i = 0; i < 4; ++i)
      #pragma unroll
      for (int j = 0; j < 4; ++j) { a5[i][j] = (f32x4){0,0,0,0}; a6[i][j] = (f32x4){0,0,0,0}; }
    for (int kt = 0; kt < 16; ++kt) {
      stageW(bufW,  W5, 512, kt*32, nb, 719);
      stageW(bufW2, W6, 512, kt*32, nb, 719);
      __syncthreads();
      bf16x8 af[4], b5f[4], b6f[4];
      #pragma unroll
      for (int i = 0; i < 4; ++i) af[i] = ldA(bufX, XLD, 0, i, kt);
      #pragma unroll
      for (int j = 0; j < 4; ++j) { b5f[j] = ldB(bufW, j); b6f[j] = ldB(bufW2, j); }
      #pragma unroll
      for (int i = 0; i < 4; ++i)
        #pragma unroll
        for (int j = 0; j < 4; ++j) {
          a5[i][j] = __builtin_amdgcn_mfma_f32_16x16x32_bf16(af[i], b5f[j], a5[i][j], 0, 0, 0);
          a6[i][j] = __builtin_amdgcn_mfma_f32_16x16x32_bf16(af[i], b6f[j], a6[i][j], 0, 0, 0);
        }
      __syncthreads();
    }
    #pragma unroll
    for (int i = 0; i < 4; ++i)
      #pragma unroll
      for (int j = 0; j < 4; ++j) {
        int n = nb + wv*64 + j*16 + c16;
        if (n >= SEQ) continue;
        float bv5 = b5[n], bv6 = b6[n];
        #pragma unroll
        for (int r = 0; r < 4; ++r) {
          int m = i*16 + q4*4 + r;
          int row = m0 + m;
          if (row >= MTOT) continue;
          float z5 = a5[i][j][r] + bv5;
          float z6 = a6[i][j][r] + bv6;
          float v = z6 / (1.f + expf(-z5));
          if (sub) v -= b2f(sub[(ll)row*SEQ + n]);
          outX[(ll)row*SEQ + n] = f2b(v);
        }
      }
  }
}

// ------------------------------------------------------------------
extern "C" void kernel_launch(void* const* d_in, const int* in_sizes, int n_in,
                              void* d_out, int out_size, void* d_ws, size_t ws_size,
                              hipStream_t stream)
{
  (void)in_sizes; (void)n_in; (void)out_size; (void)ws_size;
  const float* x    = (const float*)d_in[0];
  const float* xm   = (const float*)d_in[1];
  const float* embw = (const float*)d_in[4];
  const float* embb = (const float*)d_in[5];
  const float* Wqf  = (const float*)d_in[6];
  const float* Wkf  = (const float*)d_in[7];
  const float* Wvf  = (const float*)d_in[8];
  const float* Wof  = (const float*)d_in[9];
  const float* W3f  = (const float*)d_in[10];
  const float* W4f  = (const float*)d_in[11];
  const float* bq   = (const float*)d_in[12];
  const float* bk   = (const float*)d_in[13];
  const float* bv   = (const float*)d_in[14];
  const float* bo   = (const float*)d_in[15];
  const float* b3   = (const float*)d_in[16];
  const float* b4   = (const float*)d_in[17];
  const float* W1f  = (const float*)d_in[18];
  const float* b1   = (const float*)d_in[19];
  const float* W2f  = (const float*)d_in[20];
  const float* b2   = (const float*)d_in[21];
  const float* W5f  = (const float*)d_in[22];
  const float* b5   = (const float*)d_in[23];
  const float* W6f  = (const float*)d_in[24];
  const float* b6   = (const float*)d_in[25];
  const float* ln1g = (const float*)d_in[26];
  const float* ln1b = (const float*)d_in[27];
  const float* ln2g = (const float*)d_in[28];
  const float* ln2b = (const float*)d_in[29];

  u8* ws = (u8*)d_ws;
  size_t off = 0;
  auto alloc = [&](size_t bytes) -> void* {
    void* ptr = ws + off;
    off = (off + bytes + 255) & ~(size_t)255;
    return ptr;
  };
  float* meanp = (float*)alloc((size_t)G16*ENC*4);
  float* stdp  = (float*)alloc((size_t)G16*ENC*4);
  u16* xin   = (u16*)alloc((size_t)G16*NTOK*KPAD*2);
  u16* wp    = (u16*)alloc((size_t)DM*KPAD*2);
  const int nWsm = 2*DM*DM;
  const int nWff = 2*512*DM;
  const int nW56 = 2*SEQ*512;
  u16* Wqkv = (u16*)alloc((size_t)2*768*256*2);
  u16* Wo = (u16*)alloc((size_t)nWsm*2);
  u16* W3 = (u16*)alloc((size_t)nWsm*2);
  u16* W4 = (u16*)alloc((size_t)nWsm*2);
  u16* W1 = (u16*)alloc((size_t)nWff*2);
  u16* W2 = (u16*)alloc((size_t)nWff*2);
  u16* W5 = (u16*)alloc((size_t)nW56*2);
  u16* W6 = (u16*)alloc((size_t)nW56*2);
  float* bqkv = (float*)alloc((size_t)2*768*4);
  u16* hb    = (u16*)alloc((size_t)MTOT*DM*2);
  u16* qkvb  = (u16*)alloc((size_t)MTOT*768*2);
  u16* vT    = (u16*)alloc((size_t)G16*DM*SPAD*2);
  u16* attb  = (u16*)alloc((size_t)MTOT*DM*2);
  u16* out0b = (u16*)alloc((size_t)MTOT*SEQ*2);
  u16* outFb = (u16*)alloc((size_t)MTOT*SEQ*2);

  auto gemmW = [&](const u16* A, int lda, const u16* B, int ldb, const float* bias,
                   u16* C, int ldc, int M, int N, int K, int mode) {
    dim3 grid((N + 127) / 128, (M + 127) / 128, 1);
    gemm_nt<<<grid, 256, 0, stream>>>(A, B, bias, C, M, N, K, lda, ldb, ldc, mode);
  };

  // weight conversion: one launch, 10 jobs
  CvtJobs J{};
  int nj = 0;
  auto addjob = [&](const float* s, u16* d, int n, int per, ll stride) {
    J.src[nj] = s; J.dst[nj] = d; J.n[nj] = n; J.per[nj] = per; J.stride[nj] = stride; nj++;
  };
  addjob(Wqf, Wqkv,           nWsm, 65536, 196608);
  addjob(Wkf, Wqkv + 65536,   nWsm, 65536, 196608);
  addjob(Wvf, Wqkv + 131072,  nWsm, 65536, 196608);
  addjob(Wof, Wo, nWsm, 0, 0);
  addjob(W3f, W3, nWsm, 0, 0);
  addjob(W4f, W4, nWsm, 0, 0);
  addjob(W1f, W1, nWff, 0, 0);
  addjob(W2f, W2, nWff, 0, 0);
  addjob(W5f, W5, nW56, 0, 0);
  addjob(W6f, W6, nW56, 0, 0);
  cvt_multi<<<dim3(512, 10), 256, 0, stream>>>(J);
  pack_bqkv<<<6, 256, 0, stream>>>(bq, bk, bv, bqkv);

  stats_kernel<<<64, 256, 0, stream>>>(x, meanp, stdp);
  build_xin<<<dim3(28, 23, 16), 256, 0, stream>>>(x, xm, meanp, stdp, xin);
  pack_embedw<<<256, 256, 0, stream>>>(embw, wp);

  // h = xin @ embed_w^T + embed_b
  gemmW(xin, KPAD, wp, KPAD, embb, hb, DM, MTOT, DM, KPAD, 0);

  const int NBLK = (MTOT + 63) / 64;   // 217
  for (int l = 0; l < 2; ++l) {
    const ll wOff  = (ll)l * DM * DM;
    const ll wOff1 = (ll)l * 512 * DM;
    const ll wOff5 = (ll)l * SEQ * 512;
    // fused qkv (q pre-scaled by scale*log2e)
    gemmW(hb, DM, Wqkv + (ll)l*768*256, 256, bqkv + l*768, qkvb, 768,
          MTOT, 768, DM, 5);
    transpose_v<<<dim3(8, 28, 16), 256, 0, stream>>>(qkvb + 512, 768, vT);
    flash_attn<<<dim3(7, 128), 256, 0, stream>>>(qkvb, qkvb + 256, 768, vT, attb);

    ffn_fused<<<NBLK, 256, 0, stream>>>(
        attb, hb,
        Wo + wOff, W1 + wOff1, W2 + wOff1, W3 + wOff, W4 + wOff,
        W5 + wOff5, W6 + wOff5,
        bo + l*DM, b1 + l*512, b2 + l*DM, b3 + l*DM, b4 + l*DM,
        b5 + l*SEQ, b6 + l*SEQ,
        ln1g + l*DM, ln1b + l*DM, ln2g + l*DM, ln2b + l*DM,
        (l == 0) ? nullptr : out0b,
        (l == 0) ? out0b : outFb);
  }

  final_combine<<<dim3(27, 23, 8), 256, 0, stream>>>(outFb, meanp, stdp, (float*)d_out);
}

// Round 8
// 734.292 us; speedup vs baseline: 1.3568x; 1.3568x over previous
//
#include <hip/hip_runtime.h>
#include <cstdint>
#include <cstddef>

#define DEV __device__ __forceinline__
#define AS1 __attribute__((address_space(1)))
#define AS3 __attribute__((address_space(3)))

typedef unsigned short u16;
typedef unsigned char u8;
typedef long long ll;

typedef __attribute__((ext_vector_type(8))) __bf16 bf16x8;
typedef __attribute__((ext_vector_type(8))) unsigned short u16x8;
typedef __attribute__((ext_vector_type(4))) float f32x4;

static constexpr int SEQ  = 720;
static constexpr int ENC  = 862;
static constexpr int NTOK = 866;            // ENC + MARK
static constexpr int DM   = 256;
static constexpr int G16  = 16;             // B * T_SCALES
static constexpr int MTOT = G16 * NTOK;     // 13856
static constexpr int KPAD = 768;            // SEQ padded to multiple of 64
static constexpr int SPAD = 896;            // 866 keys padded to multiple of 32
static constexpr float SC2 = 0.17677669529663689f * 1.4426950408889634f; // scale*log2e

DEV float b2f(u16 v){ union { unsigned u; float f; } x; x.u = ((unsigned)v) << 16; return x.f; }
DEV u16 f2b(float f){ union { float f; unsigned u; } x; x.f = f;
  unsigned r = x.u + 0x7fffu + ((x.u >> 16) & 1u); return (u16)(r >> 16); }
DEV bf16x8 as_bf(u16x8 v){ return __builtin_bit_cast(bf16x8, v); }

// async global->LDS, 16B per lane; LDS base wave-uniform
DEV void g2l(const u16* g, u16* l){
  __builtin_amdgcn_global_load_lds((AS1 void*)g, (AS3 void*)l, 16, 0, 0);
}

// XCD-aware remap: XCD (L%8) owns a contiguous band of work-items
DEV int xcd_work(){
  int L = blockIdx.y * gridDim.x + blockIdx.x;
  int T = gridDim.x * gridDim.y;
  int x = L & 7, k = L >> 3;
  int q = T >> 3, r = T & 7;
  int mn = x < r ? x : r;
  return x*q + mn + k;
}

// ------------------------------------------------------------------
struct CvtJobs {
  const float* src[10];
  u16* dst[10];
  int n[10];
  int per[10];
  ll stride[10];
};
__global__ __launch_bounds__(256) void cvt_multi(CvtJobs J)
{
  int j = blockIdx.y;
  const float* s = J.src[j];
  u16* d = J.dst[j];
  int n = J.n[j], per = J.per[j];
  ll st = J.stride[j];
  for (int i = blockIdx.x*256 + threadIdx.x; i < n; i += gridDim.x*256) {
    ll di = per ? ((ll)(i/per)*st + (i%per)) : (ll)i;
    d[di] = f2b(s[i]);
  }
}

__global__ __launch_bounds__(256) void pack_bqkv(const float* __restrict__ bq,
                                                 const float* __restrict__ bk,
                                                 const float* __restrict__ bv,
                                                 float* __restrict__ out)
{
  int idx = blockIdx.x*256 + threadIdx.x;
  if (idx >= 1536) return;
  int l = idx / 768, j = idx % 768;
  float v;
  if (j < 256)      v = bq[l*256 + j];
  else if (j < 512) v = bk[l*256 + j - 256];
  else              v = bv[l*256 + j - 512];
  out[idx] = v;
}

// ------------------------------------------------------------------
__global__ __launch_bounds__(256) void stats_kernel(const float* __restrict__ x,
                                                    float* __restrict__ meanp,
                                                    float* __restrict__ stdp)
{
  int g = blockIdx.x >> 2;
  int c = ((blockIdx.x & 3) << 8) + threadIdx.x;
  if (c >= ENC) return;
  const float* xp = x + (ll)g * SEQ * ENC + c;
  float s = 0.f, q = 0.f;
  for (int t = 0; t < SEQ; ++t) {
    float v = xp[(ll)t * ENC];
    s += v; q += v * v;
  }
  float mn  = s * (1.f / SEQ);
  float var = q * (1.f / SEQ) - mn * mn;
  var = var < 0.f ? 0.f : var;
  meanp[g * ENC + c] = mn;
  stdp [g * ENC + c] = sqrtf(var + 1e-5f);
}

// ------------------------------------------------------------------
__global__ __launch_bounds__(256) void build_xin(const float* __restrict__ x,
                                                 const float* __restrict__ xm,
                                                 const float* __restrict__ meanp,
                                                 const float* __restrict__ stdp,
                                                 u16* __restrict__ xin)
{
  int g  = blockIdx.z;
  int c0 = blockIdx.x << 5, s0 = blockIdx.y << 5;
  __shared__ float tl[32][33];
  __shared__ float mn[32], isd[32];
  int tid = threadIdx.x;
  if (tid < 32) {
    int c = c0 + tid;
    float m = 0.f, s = 1.f;
    if (c < ENC) { m = meanp[g*ENC + c]; s = stdp[g*ENC + c]; }
    mn[tid] = m; isd[tid] = 1.f / s;
  }
  __syncthreads();
  int ci = tid & 31, r = tid >> 5;
  #pragma unroll
  for (int p = 0; p < 4; ++p) {
    int sl = r + (p << 3);
    int s = s0 + sl, c = c0 + ci;
    float v = 0.f;
    if (s < SEQ && c < NTOK) {
      if (c < ENC) v = (x[((ll)g*SEQ + s)*ENC + c] - mn[ci]) * isd[ci];
      else         v = xm[((ll)g*SEQ + s)*4 + (c - ENC)];
    }
    tl[sl][ci] = v;
  }
  __syncthreads();
  int si = tid & 31;
  #pragma unroll
  for (int p = 0; p < 4; ++p) {
    int cl = r + (p << 3);
    int c = c0 + cl;
    if (c < NTOK) xin[((ll)g*NTOK + c)*KPAD + s0 + si] = f2b(tl[si][cl]);
  }
}

// ------------------------------------------------------------------
__global__ __launch_bounds__(256) void pack_embedw(const float* __restrict__ ew,
                                                   u16* __restrict__ wp)
{
  int row = blockIdx.x;
  for (int c = threadIdx.x; c < KPAD; c += 256)
    wp[row*KPAD + c] = (c < SEQ) ? f2b(ew[row*SEQ + c]) : (u16)0;
}

// ------------------------------------------------------------------
__global__ __launch_bounds__(256) void transpose_v(const u16* __restrict__ v, int ldv,
                                                   u16* __restrict__ vT)
{
  int g = blockIdx.z;
  int d0 = blockIdx.x << 5, s0 = blockIdx.y << 5;
  __shared__ u16 tl[32][33];
  int tid = threadIdx.x;
  int di = tid & 31, r = tid >> 5;
  #pragma unroll
  for (int p = 0; p < 4; ++p) {
    int sl = r + (p << 3);
    int s = s0 + sl;
    u16 val = 0;
    if (s < NTOK) val = v[((ll)g*NTOK + s)*ldv + d0 + di];
    tl[sl][di] = val;
  }
  __syncthreads();
  int si = tid & 31;
  #pragma unroll
  for (int p = 0; p < 4; ++p) {
    int dl = r + (p << 3);
    vT[((ll)g*DM + d0 + dl)*SPAD + s0 + si] = tl[si][dl];
  }
}

// ------------------------------------------------------------------
// flash attention, fixed-max softmax (Q pre-scaled by scale*log2e).
// ------------------------------------------------------------------
__global__ __launch_bounds__(256) void flash_attn(const u16* __restrict__ qb,
                                                  const u16* __restrict__ kb,
                                                  int ldqk,
                                                  const u16* __restrict__ vT,
                                                  u16* __restrict__ attb)
{
  const int w = xcd_work();
  const int gh = w / 7;
  const int g = gh >> 3, h = gh & 7;
  const int q0 = (w % 7) * 128;
  const int tid = threadIdx.x, wv = tid >> 6, lane = tid & 63;
  const int q4 = lane >> 4, c16 = lane & 15;
  constexpr int PLD = 136;

  __shared__ __attribute__((aligned(16))) u16 Qs[128*32];
  __shared__ __attribute__((aligned(16))) u16 Ks[128*32];
  __shared__ __attribute__((aligned(16))) u16 Vs[32*PLD];
  __shared__ __attribute__((aligned(16))) u16 Ps[4][32*PLD];

  {
    int r = tid >> 1, sg = (tid & 1) << 4;
    int row = q0 + r; if (row > NTOK-1) row = NTOK-1;
    const u16* src = qb + ((ll)(g*NTOK + row))*ldqk + h*32 + sg;
    *(uint4*)&Qs[r*32 + sg]     = *(const uint4*)src;
    *(uint4*)&Qs[r*32 + sg + 8] = *(const uint4*)(src + 8);
  }
  __syncthreads();

  bf16x8 qf[2];
  qf[0] = as_bf(*(const u16x8*)&Qs[(wv*32 +      c16)*32 + q4*8]);
  qf[1] = as_bf(*(const u16x8*)&Qs[(wv*32 + 16 + c16)*32 + q4*8]);

  float lsum[2][4] = {{0,0,0,0},{0,0,0,0}};
  f32x4 oacc[2][2];
  oacc[0][0] = (f32x4){0,0,0,0}; oacc[0][1] = (f32x4){0,0,0,0};
  oacc[1][0] = (f32x4){0,0,0,0}; oacc[1][1] = (f32x4){0,0,0,0};

  for (int kt = 0; kt < 7; ++kt) {
    const int k0 = kt * 128;
    if (kt) __syncthreads();
    {
      int r = tid >> 1, sg = (tid & 1) << 4;
      int row = k0 + r; if (row > NTOK-1) row = NTOK-1;
      const u16* src = kb + ((ll)(g*NTOK + row))*ldqk + h*32 + sg;
      *(uint4*)&Ks[r*32 + sg]     = *(const uint4*)src;
      *(uint4*)&Ks[r*32 + sg + 8] = *(const uint4*)(src + 8);
    }
    {
      int e = tid >> 3, sg = (tid & 7) << 4;
      const u16* src = vT + ((ll)(g*DM + h*32 + e))*SPAD + k0 + sg;
      *(uint4*)&Vs[e*PLD + sg]     = *(const uint4*)src;
      *(uint4*)&Vs[e*PLD + sg + 8] = *(const uint4*)(src + 8);
    }
    __syncthreads();

    f32x4 s[2][8];
    #pragma unroll
    for (int i = 0; i < 2; ++i)
      #pragma unroll
      for (int j = 0; j < 8; ++j) s[i][j] = (f32x4){0,0,0,0};
    #pragma unroll
    for (int j = 0; j < 8; ++j) {
      bf16x8 kf = as_bf(*(const u16x8*)&Ks[(j*16 + c16)*32 + q4*8]);
      s[0][j] = __builtin_amdgcn_mfma_f32_16x16x32_bf16(qf[0], kf, s[0][j], 0, 0, 0);
      s[1][j] = __builtin_amdgcn_mfma_f32_16x16x32_bf16(qf[1], kf, s[1][j], 0, 0, 0);
    }
    if (kt == 6) {
      #pragma unroll
      for (int j = 0; j < 8; ++j) {
        if (k0 + j*16 + c16 >= NTOK) {
          #pragma unroll
          for (int r = 0; r < 4; ++r) { s[0][j][r] = -1e30f; s[1][j][r] = -1e30f; }
        }
      }
    }

    #pragma unroll
    for (int i = 0; i < 2; ++i)
      #pragma unroll
      for (int j = 0; j < 8; ++j)
        #pragma unroll
        for (int r = 0; r < 4; ++r) {
          float p = exp2f(s[i][j][r]);
          lsum[i][r] += p;
          unsigned u = __builtin_bit_cast(unsigned, p);
          Ps[wv][(i*16 + q4*4 + r)*PLD + j*16 + c16] = (u16)(u >> 16);
        }

    #pragma unroll
    for (int kk = 0; kk < 4; ++kk) {
      bf16x8 af0 = as_bf(*(const u16x8*)&Ps[wv][(     c16)*PLD + kk*32 + q4*8]);
      bf16x8 af1 = as_bf(*(const u16x8*)&Ps[wv][(16 + c16)*PLD + kk*32 + q4*8]);
      bf16x8 b0  = as_bf(*(const u16x8*)&Vs[(     c16)*PLD + kk*32 + q4*8]);
      bf16x8 b1  = as_bf(*(const u16x8*)&Vs[(16 + c16)*PLD + kk*32 + q4*8]);
      oacc[0][0] = __builtin_amdgcn_mfma_f32_16x16x32_bf16(af0, b0, oacc[0][0], 0, 0, 0);
      oacc[0][1] = __builtin_amdgcn_mfma_f32_16x16x32_bf16(af0, b1, oacc[0][1], 0, 0, 0);
      oacc[1][0] = __builtin_amdgcn_mfma_f32_16x16x32_bf16(af1, b0, oacc[1][0], 0, 0, 0);
      oacc[1][1] = __builtin_amdgcn_mfma_f32_16x16x32_bf16(af1, b1, oacc[1][1], 0, 0, 0);
    }
  }

  float linv[2][4];
  #pragma unroll
  for (int i = 0; i < 2; ++i)
    #pragma unroll
    for (int r = 0; r < 4; ++r) {
      float t = lsum[i][r];
      t += __shfl_xor(t, 1, 64);
      t += __shfl_xor(t, 2, 64);
      t += __shfl_xor(t, 4, 64);
      t += __shfl_xor(t, 8, 64);
      linv[i][r] = 1.f / t;
    }
  #pragma unroll
  for (int i = 0; i < 2; ++i)
    #pragma unroll
    for (int jn = 0; jn < 2; ++jn)
      #pragma unroll
      for (int r = 0; r < 4; ++r) {
        int row = q0 + wv*32 + i*16 + q4*4 + r;
        if (row < NTOK)
          attb[((ll)(g*NTOK + row))*DM + h*32 + jn*16 + c16] =
            f2b(oacc[i][jn][r] * linv[i][r]);
      }
}

// ------------------------------------------------------------------
__global__ __launch_bounds__(256) void ln_rows(const u16* __restrict__ in1,
                                               const u16* __restrict__ in2,
                                               int ld1, int ld2,
                                               const float* __restrict__ gamma,
                                               const float* __restrict__ beta,
                                               u16* __restrict__ out, int ldo, int Mrows)
{
  int row = blockIdx.x*4 + (threadIdx.x >> 6);
  int lane = threadIdx.x & 63;
  if (row >= Mrows) return;
  float xv[4];
  ushort4 a = *(const ushort4*)(in1 + (ll)row*ld1 + lane*4);
  xv[0]=b2f(a.x); xv[1]=b2f(a.y); xv[2]=b2f(a.z); xv[3]=b2f(a.w);
  if (in2) {
    ushort4 b = *(const ushort4*)(in2 + (ll)row*ld2 + lane*4);
    xv[0]-=b2f(b.x); xv[1]-=b2f(b.y); xv[2]-=b2f(b.z); xv[3]-=b2f(b.w);
  }
  float s = xv[0]+xv[1]+xv[2]+xv[3];
  #pragma unroll
  for (int o = 32; o > 0; o >>= 1) s += __shfl_xor(s, o, 64);
  float mean = s * (1.f/256.f);
  float d0=xv[0]-mean, d1=xv[1]-mean, d2=xv[2]-mean, d3=xv[3]-mean;
  float q = d0*d0 + d1*d1 + d2*d2 + d3*d3;
  #pragma unroll
  for (int o = 32; o > 0; o >>= 1) q += __shfl_xor(q, o, 64);
  float rstd = 1.f / sqrtf(q * (1.f/256.f) + 1e-5f);
  float4 gv = *(const float4*)(gamma + lane*4);
  float4 bb = *(const float4*)(beta  + lane*4);
  ushort4 o4;
  o4.x = f2b(d0*rstd*gv.x + bb.x);
  o4.y = f2b(d1*rstd*gv.y + bb.y);
  o4.z = f2b(d2*rstd*gv.z + bb.z);
  o4.w = f2b(d3*rstd*gv.w + bb.w);
  *(ushort4*)(out + (ll)row*ldo + lane*4) = o4;
}

// ------------------------------------------------------------------
__global__ __launch_bounds__(256) void final_combine(const u16* __restrict__ outF,
                                                     const float* __restrict__ meanp,
                                                     const float* __restrict__ stdp,
                                                     float* __restrict__ dout)
{
  int b = blockIdx.z;
  int c0 = blockIdx.x << 5, s0 = blockIdx.y << 5;
  __shared__ float tl[32][33];
  int tid = threadIdx.x;
  int si = tid & 31, r = tid >> 5;
  #pragma unroll
  for (int p = 0; p < 4; ++p) {
    int cl = r + (p << 3);
    int c = c0 + cl, s = s0 + si;
    float accv = 0.f;
    #pragma unroll
    for (int t = 0; t < 2; ++t) {
      int g = b*2 + t;
      if (c < ENC && s < SEQ) {
        float v = b2f(outF[((ll)(g*NTOK + c))*SEQ + s]);
        accv += 0.5f * (v * stdp[g*ENC + c] + meanp[g*ENC + c]);
      }
    }
    tl[cl][si] = accv;
  }
  __syncthreads();
  int ci = tid & 31;
  #pragma unroll
  for (int p = 0; p < 4; ++p) {
    int sl = r + (p << 3);
    int s = s0 + sl, c = c0 + ci;
    if (s < SEQ && c < ENC)
      dout[((ll)b*SEQ + s)*ENC + c] = tl[ci][sl];
  }
}

// ------------------------------------------------------------------
// NT GEMM, BK=64 as two 32-wide panels (g2l-compatible layout).
// XCD swizzle. modes: 0 store, 1 gelu, 2 (store y; aux2=aux1-y), 5 qkv
// ------------------------------------------------------------------
__global__ __launch_bounds__(256) void gemm_nt(
    const u16* __restrict__ A, const u16* __restrict__ B,
    const float* __restrict__ bias, u16* __restrict__ C,
    const u16* __restrict__ aux1, u16* __restrict__ aux2,
    int M, int N, int K, int lda, int ldb, int ldc, int ld1, int ld2, int mode)
{
  __shared__ __attribute__((aligned(16))) u16 As[2][128*32];
  __shared__ __attribute__((aligned(16))) u16 Bs[2][128*32];

  const int tid  = threadIdx.x;
  const int wv   = tid >> 6;
  const int lane = tid & 63;
  const int q4   = lane >> 4;
  const int c16  = lane & 15;

  const int w = xcd_work();
  const int n0 = (w % gridDim.x) * 128;
  const int m0 = (w / gridDim.x) * 128;
  const int wm = (wv >> 1) * 64;
  const int wn = (wv & 1) * 64;

  const int lrow = lane >> 2;          // 0..15
  const int lcol = (lane & 3) << 3;    // 0,8,16,24
  int am0 = m0 + wv*32 + lrow;      if (am0 >= M) am0 = M-1;
  int am1 = m0 + wv*32 + 16 + lrow; if (am1 >= M) am1 = M-1;
  int bn0 = n0 + wv*32 + lrow;      if (bn0 >= N) bn0 = N-1;
  int bn1 = n0 + wv*32 + 16 + lrow; if (bn1 >= N) bn1 = N-1;
  const u16* pa0 = A + (ll)am0*lda + lcol;
  const u16* pa1 = A + (ll)am1*lda + lcol;
  const u16* pb0 = B + (ll)bn0*ldb + lcol;
  const u16* pb1 = B + (ll)bn1*ldb + lcol;

  f32x4 acc[4][4];
  #pragma unroll
  for (int i = 0; i < 4; ++i)
    #pragma unroll
    for (int j = 0; j < 4; ++j) acc[i][j] = (f32x4){0,0,0,0};

  const int nk = K >> 6;
  auto issue = [&](int kt) {
    int ko = kt*64;
    #pragma unroll
    for (int c = 0; c < 2; ++c) {
      g2l(pa0 + ko + c*32, &As[c][(wv*32)*32]);
      g2l(pa1 + ko + c*32, &As[c][(wv*32 + 16)*32]);
      g2l(pb0 + ko + c*32, &Bs[c][(wv*32)*32]);
      g2l(pb1 + ko + c*32, &Bs[c][(wv*32 + 16)*32]);
    }
  };

  issue(0);
  for (int kt = 0; kt < nk; ++kt) {
    __syncthreads();
    #pragma unroll
    for (int c = 0; c < 2; ++c) {
      bf16x8 af[4], bfv[4];
      #pragma unroll
      for (int i = 0; i < 4; ++i)
        af[i] = as_bf(*(const u16x8*)&As[c][(wm + i*16 + c16)*32 + q4*8]);
      #pragma unroll
      for (int j = 0; j < 4; ++j)
        bfv[j] = as_bf(*(const u16x8*)&Bs[c][(wn + j*16 + c16)*32 + q4*8]);
      #pragma unroll
      for (int i = 0; i < 4; ++i)
        #pragma unroll
        for (int j = 0; j < 4; ++j)
          acc[i][j] = __builtin_amdgcn_mfma_f32_16x16x32_bf16(af[i], bfv[j], acc[i][j], 0, 0, 0);
    }
    if (kt + 1 < nk) { __syncthreads(); issue(kt + 1); }
  }

  #pragma unroll
  for (int i = 0; i < 4; ++i) {
    #pragma unroll
    for (int j = 0; j < 4; ++j) {
      int n = n0 + wn + j*16 + c16;
      if (n >= N) continue;
      float bv = bias ? bias[n] : 0.f;
      int mb = m0 + wm + i*16 + q4*4;
      #pragma unroll
      for (int r = 0; r < 4; ++r) {
        int m = mb + r;
        if (m >= M) continue;
        float x = acc[i][j][r] + bv;
        ll ci = (ll)m*ldc + n;
        if (mode == 0) {
          C[ci] = f2b(x);
        } else if (mode == 1) {
          C[ci] = f2b(0.5f * x * (1.f + erff(x * 0.70710678118654752f)));
        } else if (mode == 5) {
          C[ci] = f2b(n < 256 ? x * SC2 : x);
        } else { // mode 2
          C[ci] = f2b(x);
          float xl = b2f(aux1[(ll)m*ld1 + n]);
          aux2[(ll)m*ld2 + n] = f2b(xl - x);
        }
      }
    }
  }
}

// ------------------------------------------------------------------
// dual NT GEMM, BK=64 two-panel: C = sig(A B5^T+b5)*(A B6^T+b6) [- sub]
// ------------------------------------------------------------------
__global__ __launch_bounds__(256) void gemm_nt_dual(
    const u16* __restrict__ A, const u16* __restrict__ B5, const u16* __restrict__ B6,
    const float* __restrict__ bias5, const float* __restrict__ bias6,
    u16* __restrict__ C, const u16* __restrict__ sub,
    int M, int N, int K, int lda, int ldb, int ldc, int ldsub)
{
  __shared__ __attribute__((aligned(16))) u16 As[2][128*32];
  __shared__ __attribute__((aligned(16))) u16 B5s[2][64*32];
  __shared__ __attribute__((aligned(16))) u16 B6s[2][64*32];

  const int tid  = threadIdx.x;
  const int wv   = tid >> 6;
  const int lane = tid & 63;
  const int q4   = lane >> 4;
  const int c16  = lane & 15;

  const int w = xcd_work();
  const int n0 = (w % gridDim.x) * 64;
  const int m0 = (w / gridDim.x) * 128;
  const int wm = (wv >> 1) * 64;
  const int wn = (wv & 1) * 32;

  const int lrow = lane >> 2;
  const int lcol = (lane & 3) << 3;
  int am0 = m0 + wv*32 + lrow;      if (am0 >= M) am0 = M-1;
  int am1 = m0 + wv*32 + 16 + lrow; if (am1 >= M) am1 = M-1;
  int bn  = n0 + wv*16 + lrow;      if (bn  >= N) bn  = N-1;
  const u16* pa0 = A  + (ll)am0*lda + lcol;
  const u16* pa1 = A  + (ll)am1*lda + lcol;
  const u16* p5  = B5 + (ll)bn*ldb + lcol;
  const u16* p6  = B6 + (ll)bn*ldb + lcol;

  f32x4 a5[4][2], a6[4][2];
  #pragma unroll
  for (int i = 0; i < 4; ++i)
    #pragma unroll
    for (int j = 0; j < 2; ++j) { a5[i][j] = (f32x4){0,0,0,0}; a6[i][j] = (f32x4){0,0,0,0}; }

  const int nk = K >> 6;
  auto issue = [&](int kt) {
    int ko = kt*64;
    #pragma unroll
    for (int c = 0; c < 2; ++c) {
      g2l(pa0 + ko + c*32, &As[c][(wv*32)*32]);
      g2l(pa1 + ko + c*32, &As[c][(wv*32 + 16)*32]);
      g2l(p5 + ko + c*32, &B5s[c][(wv*16)*32]);
      g2l(p6 + ko + c*32, &B6s[c][(wv*16)*32]);
    }
  };

  issue(0);
  for (int kt = 0; kt < nk; ++kt) {
    __syncthreads();
    #pragma unroll
    for (int c = 0; c < 2; ++c) {
      bf16x8 af[4], b5f[2], b6f[2];
      #pragma unroll
      for (int i = 0; i < 4; ++i)
        af[i] = as_bf(*(const u16x8*)&As[c][(wm + i*16 + c16)*32 + q4*8]);
      #pragma unroll
      for (int j = 0; j < 2; ++j) {
        b5f[j] = as_bf(*(const u16x8*)&B5s[c][(wn + j*16 + c16)*32 + q4*8]);
        b6f[j] = as_bf(*(const u16x8*)&B6s[c][(wn + j*16 + c16)*32 + q4*8]);
      }
      #pragma unroll
      for (int i = 0; i < 4; ++i)
        #pragma unroll
        for (int j = 0; j < 2; ++j) {
          a5[i][j] = __builtin_amdgcn_mfma_f32_16x16x32_bf16(af[i], b5f[j], a5[i][j], 0, 0, 0);
          a6[i][j] = __builtin_amdgcn_mfma_f32_16x16x32_bf16(af[i], b6f[j], a6[i][j], 0, 0, 0);
        }
    }
    if (kt + 1 < nk) { __syncthreads(); issue(kt + 1); }
  }

  #pragma unroll
  for (int i = 0; i < 4; ++i) {
    #pragma unroll
    for (int j = 0; j < 2; ++j) {
      int n = n0 + wn + j*16 + c16;
      if (n >= N) continue;
      float bv5 = bias5[n], bv6 = bias6[n];
      int mb = m0 + wm + i*16 + q4*4;
      #pragma unroll
      for (int r = 0; r < 4; ++r) {
        int m = mb + r;
        if (m >= M) continue;
        float z5 = a5[i][j][r] + bv5;
        float z6 = a6[i][j][r] + bv6;
        float v = z6 / (1.f + expf(-z5));
        if (sub) v -= b2f(sub[(ll)m*ldsub + n]);
        C[(ll)m*ldc + n] = f2b(v);
      }
    }
  }
}

// ------------------------------------------------------------------
extern "C" void kernel_launch(void* const* d_in, const int* in_sizes, int n_in,
                              void* d_out, int out_size, void* d_ws, size_t ws_size,
                              hipStream_t stream)
{
  (void)in_sizes; (void)n_in; (void)out_size; (void)ws_size;
  const float* x    = (const float*)d_in[0];
  const float* xm   = (const float*)d_in[1];
  const float* embw = (const float*)d_in[4];
  const float* embb = (const float*)d_in[5];
  const float* Wqf  = (const float*)d_in[6];
  const float* Wkf  = (const float*)d_in[7];
  const float* Wvf  = (const float*)d_in[8];
  const float* Wof  = (const float*)d_in[9];
  const float* W3f  = (const float*)d_in[10];
  const float* W4f  = (const float*)d_in[11];
  const float* bq   = (const float*)d_in[12];
  const float* bk   = (const float*)d_in[13];
  const float* bv   = (const float*)d_in[14];
  const float* bo   = (const float*)d_in[15];
  const float* b3   = (const float*)d_in[16];
  const float* b4   = (const float*)d_in[17];
  const float* W1f  = (const float*)d_in[18];
  const float* b1   = (const float*)d_in[19];
  const float* W2f  = (const float*)d_in[20];
  const float* b2   = (const float*)d_in[21];
  const float* W5f  = (const float*)d_in[22];
  const float* b5   = (const float*)d_in[23];
  const float* W6f  = (const float*)d_in[24];
  const float* b6   = (const float*)d_in[25];
  const float* ln1g = (const float*)d_in[26];
  const float* ln1b = (const float*)d_in[27];
  const float* ln2g = (const float*)d_in[28];
  const float* ln2b = (const float*)d_in[29];

  u8* ws = (u8*)d_ws;
  size_t off = 0;
  auto alloc = [&](size_t bytes) -> void* {
    void* ptr = ws + off;
    off = (off + bytes + 255) & ~(size_t)255;
    return ptr;
  };
  float* meanp = (float*)alloc((size_t)G16*ENC*4);
  float* stdp  = (float*)alloc((size_t)G16*ENC*4);
  u16* xin   = (u16*)alloc((size_t)G16*NTOK*KPAD*2);
  u16* wp    = (u16*)alloc((size_t)DM*KPAD*2);
  const int nWsm = 2*DM*DM;
  const int nWff = 2*512*DM;
  const int nW56 = 2*SEQ*512;
  u16* Wqkv = (u16*)alloc((size_t)2*768*256*2);
  u16* Wo = (u16*)alloc((size_t)nWsm*2);
  u16* W3 = (u16*)alloc((size_t)nWsm*2);
  u16* W4 = (u16*)alloc((size_t)nWsm*2);
  u16* W1 = (u16*)alloc((size_t)nWff*2);
  u16* W2 = (u16*)alloc((size_t)nWff*2);
  u16* W5 = (u16*)alloc((size_t)nW56*2);
  u16* W6 = (u16*)alloc((size_t)nW56*2);
  float* bqkv = (float*)alloc((size_t)2*768*4);
  u16* hb    = (u16*)alloc((size_t)MTOT*DM*2);
  u16* qkvb  = (u16*)alloc((size_t)MTOT*768*2);
  u16* vT    = (u16*)alloc((size_t)G16*DM*SPAD*2);
  u16* attb  = (u16*)alloc((size_t)MTOT*DM*2);
  u16* catb  = (u16*)alloc((size_t)MTOT*512*2);
  u16* xlnb  = (u16*)alloc((size_t)MTOT*DM*2);
  u16* t1b   = (u16*)alloc((size_t)MTOT*512*2);
  u16* xsb   = (u16*)alloc((size_t)MTOT*DM*2);
  u16* hhb   = (u16*)alloc((size_t)MTOT*DM*2);
  u16* out0b = (u16*)alloc((size_t)MTOT*SEQ*2);
  u16* outFb = (u16*)alloc((size_t)MTOT*SEQ*2);

  auto gemmW = [&](const u16* A, int lda, const u16* B, int ldb, const float* bias,
                   u16* C, int ldc, int M, int N, int K, int mode,
                   const u16* a1, int ld1, u16* a2, int ld2) {
    dim3 grid((N + 127) / 128, (M + 127) / 128, 1);
    gemm_nt<<<grid, 256, 0, stream>>>(A, B, bias, C, a1, a2, M, N, K,
                                      lda, ldb, ldc, ld1, ld2, mode);
  };
  auto gemmD = [&](const u16* A, int lda, const u16* B5p, const u16* B6p, int ldb,
                   const float* bias5, const float* bias6, u16* C, int ldc,
                   const u16* sub, int ldsub, int M, int N, int K) {
    dim3 grid((N + 63) / 64, (M + 127) / 128, 1);
    gemm_nt_dual<<<grid, 256, 0, stream>>>(A, B5p, B6p, bias5, bias6, C, sub,
                                           M, N, K, lda, ldb, ldc, ldsub);
  };

  // weight conversion: one launch, 10 jobs
  CvtJobs J{};
  int nj = 0;
  auto addjob = [&](const float* s, u16* d, int n, int per, ll stride) {
    J.src[nj] = s; J.dst[nj] = d; J.n[nj] = n; J.per[nj] = per; J.stride[nj] = stride; nj++;
  };
  addjob(Wqf, Wqkv,           nWsm, 65536, 196608);
  addjob(Wkf, Wqkv + 65536,   nWsm, 65536, 196608);
  addjob(Wvf, Wqkv + 131072,  nWsm, 65536, 196608);
  addjob(Wof, Wo, nWsm, 0, 0);
  addjob(W3f, W3, nWsm, 0, 0);
  addjob(W4f, W4, nWsm, 0, 0);
  addjob(W1f, W1, nWff, 0, 0);
  addjob(W2f, W2, nWff, 0, 0);
  addjob(W5f, W5, nW56, 0, 0);
  addjob(W6f, W6, nW56, 0, 0);
  cvt_multi<<<dim3(512, 10), 256, 0, stream>>>(J);
  pack_bqkv<<<6, 256, 0, stream>>>(bq, bk, bv, bqkv);

  stats_kernel<<<64, 256, 0, stream>>>(x, meanp, stdp);
  build_xin<<<dim3(28, 24, 16), 256, 0, stream>>>(x, xm, meanp, stdp, xin);
  pack_embedw<<<256, 256, 0, stream>>>(embw, wp);

  // h = xin @ embed_w^T + embed_b
  gemmW(xin, KPAD, wp, KPAD, embb, hb, DM, MTOT, DM, KPAD, 0, nullptr, 0, nullptr, 0);

  for (int l = 0; l < 2; ++l) {
    const ll wOff = (ll)l * DM * DM;
    // fused qkv (q pre-scaled by scale*log2e)
    gemmW(hb, DM, Wqkv + (ll)l*768*256, 256, bqkv + l*768, qkvb, 768,
          MTOT, 768, DM, 5, nullptr, 0, nullptr, 0);
    transpose_v<<<dim3(8, 28, 16), 256, 0, stream>>>(qkvb + 512, 768, vT);

    flash_attn<<<dim3(7, 128), 256, 0, stream>>>(qkvb, qkvb + 256, 768, vT, attb);

    // x_att -> cat[:, 0:256]
    gemmW(attb, DM, Wo + wOff, DM, bo + l*DM, catb, 512, MTOT, DM, DM, 0, nullptr, 0, nullptr, 0);
    // x_ln = LN(h - x_att)
    ln_rows<<<MTOT/4, 256, 0, stream>>>(hb, catb, DM, 512, ln1g + l*DM, ln1b + l*DM, xlnb, DM, MTOT);
    // t1 = gelu(x_ln @ W1^T + b1)
    gemmW(xlnb, DM, W1 + (ll)l*512*DM, DM, b1 + l*512, t1b, 512, MTOT, 512, DM, 1, nullptr, 0, nullptr, 0);
    // y -> cat[:, 256:512]; xs = x_ln - y
    gemmW(t1b, 512, W2 + (ll)l*DM*512, 512, b2 + l*DM, catb + 256, 512, MTOT, DM, 512, 2, xlnb, DM, xsb, DM);
    // hh = sigmoid(xs W3^T + b3) * (xs W4^T + b4)
    gemmD(xsb, DM, W3 + wOff, W4 + wOff, DM, b3 + l*DM, b4 + l*DM, hhb, DM,
          nullptr, 0, MTOT, DM, DM);
    // h = LN(hh)
    ln_rows<<<MTOT/4, 256, 0, stream>>>(hhb, nullptr, DM, 0, ln2g + l*DM, ln2b + l*DM, hb, DM, MTOT);
    // out = sigmoid(cat W5^T + b5) * (cat W6^T + b6)  [- out0 on layer 1]
    if (l == 0)
      gemmD(catb, 512, W5 + (ll)l*SEQ*512, W6 + (ll)l*SEQ*512, 512,
            b5 + l*SEQ, b6 + l*SEQ, out0b, SEQ, nullptr, 0, MTOT, SEQ, 512);
    else
      gemmD(catb, 512, W5 + (ll)l*SEQ*512, W6 + (ll)l*SEQ*512, 512,
            b5 + l*SEQ, b6 + l*SEQ, outFb, SEQ, out0b, SEQ, MTOT, SEQ, 512);
  }

  final_combine<<<dim3(27, 23, 8), 256, 0, stream>>>(outFb, meanp, stdp, (float*)d_out);
}